// Round 1
// baseline (1624.620 us; speedup 1.0000x reference)
//
#include <hip/hip_runtime.h>
#include <hip/hip_bf16.h>
#include <math.h>

// FactorizedVectorQuantizer for MI355X (gfx950)
//
// rows = 32*32*32 = 32768, features 256 = 128 shape + 128 color
// shape codebook 8192x128, color codebook 512x128
//
// Numerics: must reproduce numpy fp32 pipeline
//   D = ( (S_i + t_j) - 2*dot(x_i, w_j) )  all fp32 rounds, argmin lowest-index
// dot accumulated as a single serial ascending fp32 FMA chain (matches BLAS
// microkernel accumulation order as closely as possible).
// Straight-through output must be fp32(f + fp32(q - f)), not q.

#define NROWS   32768
#define NSHAPE  8192
#define NCOLOR  512
#define HALF    128

#define NCHS    16      // shape code chunks
#define CS      512     // codes per shape chunk
#define NCHC    4       // color code chunks
#define CC      128     // codes per color chunk
#define ROWBLK  256
#define NRB     (NROWS / ROWBLK)   // 128 row blocks

// workspace byte offsets
#define OFF_TS    0u                                  // f32[8192]
#define OFF_TC    32768u                              // f32[512]
#define OFF_CNT_S 34816u                              // u32[8192]
#define OFF_CNT_C 67584u                              // u32[512]
#define OFF_LOSS  69632u                              // double
#define OFF_PVS   69648u                              // f32[NROWS*NCHS]
#define OFF_PIS   (OFF_PVS + NROWS*NCHS*4u)           // i32[NROWS*NCHS]
#define OFF_PVC   (OFF_PIS + NROWS*NCHS*4u)           // f32[NROWS*NCHC]
#define OFF_PIC   (OFF_PVC + NROWS*NCHC*4u)           // i32[NROWS*NCHC]

__global__ __launch_bounds__(256) void codes_sq_k(
    const float* __restrict__ Ws, const float* __restrict__ Wc,
    float* __restrict__ ts, float* __restrict__ tc)
{
    int j = blockIdx.x * 256 + threadIdx.x;
    if (j < NSHAPE) {
        const float* w = Ws + (size_t)j * HALF;
        float s = 0.f;
        #pragma unroll
        for (int k = 0; k < HALF; ++k) s = fmaf(w[k], w[k], s);
        ts[j] = s;
    } else if (j - NSHAPE < NCOLOR) {
        int jc = j - NSHAPE;
        const float* w = Wc + (size_t)jc * HALF;
        float s = 0.f;
        #pragma unroll
        for (int k = 0; k < HALF; ++k) s = fmaf(w[k], w[k], s);
        tc[jc] = s;
    }
}

__global__ __launch_bounds__(256, 2) void argmin_k(
    const float* __restrict__ input,
    const float* __restrict__ Ws, const float* __restrict__ Wc,
    const float* __restrict__ ts, const float* __restrict__ tc,
    float* __restrict__ pvs, int* __restrict__ pis,
    float* __restrict__ pvc, int* __restrict__ pic)
{
    int bid = blockIdx.x;
    const float* W; const float* tv; float* pv; int* pi;
    int rowblk, chunk, ncodes, nch, featoff;
    if (bid < NRB * NCHS) {                 // shape blocks
        rowblk = bid >> 4; chunk = bid & (NCHS - 1);
        ncodes = CS; nch = NCHS; featoff = 0;
        W = Ws; tv = ts; pv = pvs; pi = pis;
    } else {                                // color blocks
        int b2 = bid - NRB * NCHS;
        rowblk = b2 >> 2; chunk = b2 & (NCHC - 1);
        ncodes = CC; nch = NCHC; featoff = HALF;
        W = Wc; tv = tc; pv = pvc; pi = pic;
    }
    int codebase = chunk * ncodes;
    int r = rowblk * ROWBLK + threadIdx.x;
    int b = r >> 10; int hw = r & 1023;
    const float* __restrict__ xin =
        input + ((size_t)b << 18) + ((size_t)featoff << 10) + hw;

    // row into registers (coalesced: lanes = consecutive hw)
    float x[HALF];
    #pragma unroll
    for (int k = 0; k < HALF; ++k) x[k] = xin[(size_t)k << 10];

    // S_i: per-row constant; any fixed order is argmin-safe
    float S = 0.f;
    #pragma unroll
    for (int k = 0; k < HALF; ++k) S = fmaf(x[k], x[k], S);

    float best = INFINITY; int bestj = 0;
    const float* __restrict__ wp = W + ((size_t)codebase << 7);
    const float* __restrict__ tp = tv + codebase;

    for (int j = 0; j < ncodes; j += 4) {
        const float* w0 = wp + ((size_t)(j + 0) << 7);
        const float* w1 = wp + ((size_t)(j + 1) << 7);
        const float* w2 = wp + ((size_t)(j + 2) << 7);
        const float* w3 = wp + ((size_t)(j + 3) << 7);
        float a0 = 0.f, a1 = 0.f, a2 = 0.f, a3 = 0.f;
        // serial ascending FMA chain per code; 4 codes for ILP.
        // w values are block-uniform -> scalar loads, SGPR operand in v_fmac.
        #pragma unroll
        for (int k = 0; k < HALF; ++k) {
            a0 = fmaf(x[k], w0[k], a0);
            a1 = fmaf(x[k], w1[k], a1);
            a2 = fmaf(x[k], w2[k], a2);
            a3 = fmaf(x[k], w3[k], a3);
        }
        float D0 = (S + tp[j + 0]) - 2.0f * a0;
        float D1 = (S + tp[j + 1]) - 2.0f * a1;
        float D2 = (S + tp[j + 2]) - 2.0f * a2;
        float D3 = (S + tp[j + 3]) - 2.0f * a3;
        if (D0 < best) { best = D0; bestj = j + 0; }
        if (D1 < best) { best = D1; bestj = j + 1; }
        if (D2 < best) { best = D2; bestj = j + 2; }
        if (D3 < best) { best = D3; bestj = j + 3; }
    }
    pv[(size_t)r * nch + chunk] = best;
    pi[(size_t)r * nch + chunk] = codebase + bestj;
}

__global__ __launch_bounds__(256) void finalize_k(
    const float* __restrict__ input,
    const float* __restrict__ Ws, const float* __restrict__ Wc,
    const float* __restrict__ pvs, const int* __restrict__ pis,
    const float* __restrict__ pvc, const int* __restrict__ pic,
    unsigned* __restrict__ cnt_s, unsigned* __restrict__ cnt_c,
    double* __restrict__ loss_sum, float* __restrict__ out)
{
    int tid = threadIdx.x;
    int r = blockIdx.x * 256 + tid;

    // reduce chunks, strict < ascending chunk => global lowest-index argmin
    float bv = INFINITY; int bi = 0;
    #pragma unroll
    for (int c = 0; c < NCHS; ++c) {
        float v = pvs[(size_t)r * NCHS + c];
        int ix = pis[(size_t)r * NCHS + c];
        if (v < bv) { bv = v; bi = ix; }
    }
    float cv = INFINITY; int ci = 0;
    #pragma unroll
    for (int c = 0; c < NCHC; ++c) {
        float v = pvc[(size_t)r * NCHC + c];
        int ix = pic[(size_t)r * NCHC + c];
        if (v < cv) { cv = v; ci = ix; }
    }
    atomicAdd(&cnt_s[bi], 1u);
    atomicAdd(&cnt_c[ci], 1u);

    int b = r >> 10; int hw = r & 1023;
    const float* __restrict__ xin = input + ((size_t)b << 18) + hw;
    float* __restrict__ op = out + ((size_t)b << 18) + hw;
    const float* __restrict__ qs = Ws + ((size_t)bi << 7);
    const float* __restrict__ qc = Wc + ((size_t)ci << 7);

    double ls = 0.0;
    #pragma unroll 8
    for (int c = 0; c < HALF; ++c) {
        float f = xin[(size_t)c << 10];
        float d = qs[c] - f;                   // fp32(q - f)
        op[(size_t)c << 10] = f + d;           // fp32(f + fp32(q - f))
        ls += (double)d * (double)d;
    }
    #pragma unroll 8
    for (int c = 0; c < HALF; ++c) {
        float f = xin[(size_t)(c + HALF) << 10];
        float d = qc[c] - f;
        op[(size_t)(c + HALF) << 10] = f + d;
        ls += (double)d * (double)d;
    }

    __shared__ double red[256];
    red[tid] = ls;
    __syncthreads();
    for (int s = 128; s > 0; s >>= 1) {
        if (tid < s) red[tid] += red[tid + s];
        __syncthreads();
    }
    if (tid == 0) atomicAdd(loss_sum, red[0]);
}

__global__ __launch_bounds__(256) void scalars_k(
    const unsigned* __restrict__ cnt_s, const unsigned* __restrict__ cnt_c,
    const double* __restrict__ loss_sum, float* __restrict__ out3)
{
    int tid = threadIdx.x;
    double es = 0.0, ec = 0.0;
    for (int j = tid; j < NSHAPE; j += 256) {
        float p = (float)cnt_s[j] / 32768.0f;
        es += (double)(p * logf(p + 1e-10f));
    }
    for (int j = tid; j < NCOLOR; j += 256) {
        float p = (float)cnt_c[j] / 32768.0f;
        ec += (double)(p * logf(p + 1e-10f));
    }
    __shared__ double r1[256], r2[256];
    r1[tid] = es; r2[tid] = ec;
    __syncthreads();
    for (int s = 128; s > 0; s >>= 1) {
        if (tid < s) { r1[tid] += r1[tid + s]; r2[tid] += r2[tid + s]; }
        __syncthreads();
    }
    if (tid == 0) {
        out3[0] = (float)(1.25 * loss_sum[0] / 8388608.0);  // q + 0.25*e latent
        out3[1] = expf(-(float)r1[0]);
        out3[2] = expf(-(float)r2[0]);
    }
}

extern "C" void kernel_launch(void* const* d_in, const int* in_sizes, int n_in,
                              void* d_out, int out_size, void* d_ws, size_t ws_size,
                              hipStream_t stream)
{
    const float* input = (const float*)d_in[0];
    const float* Ws    = (const float*)d_in[1];
    const float* Wc    = (const float*)d_in[2];
    float* out = (float*)d_out;
    char* ws = (char*)d_ws;

    float*    ts       = (float*)(ws + OFF_TS);
    float*    tc       = (float*)(ws + OFF_TC);
    unsigned* cnt_s    = (unsigned*)(ws + OFF_CNT_S);
    unsigned* cnt_c    = (unsigned*)(ws + OFF_CNT_C);
    double*   loss_sum = (double*)(ws + OFF_LOSS);
    float*    pvs      = (float*)(ws + OFF_PVS);
    int*      pis      = (int*)(ws + OFF_PIS);
    float*    pvc      = (float*)(ws + OFF_PVC);
    int*      pic      = (int*)(ws + OFF_PIC);

    // zero counts + loss accumulator (ws is 0xAA-poisoned, not re-poisoned)
    hipMemsetAsync(ws + OFF_CNT_S, 0, (OFF_LOSS + 8u) - OFF_CNT_S, stream);

    codes_sq_k<<<(NSHAPE + NCOLOR + 255) / 256, 256, 0, stream>>>(Ws, Wc, ts, tc);

    argmin_k<<<NRB * NCHS + NRB * NCHC, 256, 0, stream>>>(
        input, Ws, Wc, ts, tc, pvs, pis, pvc, pic);

    finalize_k<<<NRB, 256, 0, stream>>>(
        input, Ws, Wc, pvs, pis, pvc, pic, cnt_s, cnt_c, loss_sum, out);

    scalars_k<<<1, 256, 0, stream>>>(cnt_s, cnt_c, loss_sum, out + 8388608);
}